// Round 10
// baseline (2211.723 us; speedup 1.0000x reference)
//
#include <hip/hip_runtime.h>

typedef __attribute__((ext_vector_type(8))) short bf16x8;
typedef __attribute__((ext_vector_type(4))) float f32x4;

constexpr int BROWS  = 131072;
constexpr int DDIM   = 128;
constexpr int NTILES = BROWS / 16;   // 8192 row-tiles
constexpr int GRID   = 2048;         // 4 tiles per block

__device__ __forceinline__ short to_bf16(float f) {
    unsigned u = __builtin_bit_cast(unsigned, f);
    u = (u + 0x7FFFu + ((u >> 16) & 1u)) >> 16;   // RTNE
    return (short)u;
}

__device__ __forceinline__ bf16x8 cvt8(f32x4 lo, f32x4 hi) {
    bf16x8 r;
#pragma unroll
    for (int i = 0; i < 4; ++i) { r[i] = to_bf16(lo[i]); r[i + 4] = to_bf16(hi[i]); }
    return r;
}

// ---- Probe 1: streaming copy, m13 pattern. 64 MB read + 64 MB write / rep ----
__global__ void __launch_bounds__(256)
probe_copy32(const float* __restrict__ state, float* __restrict__ out) {
    const size_t gtid = (size_t)blockIdx.x * 256 + threadIdx.x;   // 524288 threads
    for (int rep = 0; rep < 32; ++rep) {
#pragma unroll
        for (int i = 0; i < 8; ++i) {   // 8 x f32x4 per thread = 64 MB sweep
            const size_t idx = (size_t)i * 524288 + gtid;
            f32x4 v = *reinterpret_cast<const f32x4*>(state + idx * 4);
            *reinterpret_cast<f32x4*>(out + idx * 4) = v;
        }
        asm volatile("" ::: "memory");
    }
}

// ---- Probe 2: R1 front-end only (loads + cvt + MFMA), acc sunk ----
__global__ void __launch_bounds__(256)
probe_load32(const float* __restrict__ state, const float* __restrict__ W) {
    const int lane = threadIdx.x & 63;
    const int wave = threadIdx.x >> 6;
    const int l16  = lane & 15;
    const int lq   = lane >> 4;

    bf16x8 wfrag[4][4];
#pragma unroll
    for (int ct = 0; ct < 4; ++ct) {
        const int c = wave * 64 + ct * 16 + l16;
        const float* wrow = W + (c & 127) * 256 + (c >> 7) * 128;
#pragma unroll
        for (int ks = 0; ks < 4; ++ks) {
            f32x4 lo = *reinterpret_cast<const f32x4*>(wrow + ks * 32 + lq * 8);
            f32x4 hi = *reinterpret_cast<const f32x4*>(wrow + ks * 32 + lq * 8 + 4);
            wfrag[ct][ks] = cvt8(lo, hi);
        }
    }

    for (int rep = 0; rep < 32; ++rep) {
        for (int t = blockIdx.x; t < NTILES; t += GRID) {
            const float* srow = state + (size_t)(t * 16 + l16) * DDIM + lq * 8;
            f32x4 raw[8];
#pragma unroll
            for (int ks = 0; ks < 4; ++ks) {
                raw[2 * ks]     = *reinterpret_cast<const f32x4*>(srow + ks * 32);
                raw[2 * ks + 1] = *reinterpret_cast<const f32x4*>(srow + ks * 32 + 4);
            }
            bf16x8 af[4];
#pragma unroll
            for (int ks = 0; ks < 4; ++ks) af[ks] = cvt8(raw[2 * ks], raw[2 * ks + 1]);
#pragma unroll
            for (int ct = 0; ct < 4; ++ct) {
                f32x4 acc = {0.f, 0.f, 0.f, 0.f};
#pragma unroll
                for (int ks = 0; ks < 4; ++ks)
                    acc = __builtin_amdgcn_mfma_f32_16x16x32_bf16(af[ks], wfrag[ct][ks], acc, 0, 0, 0);
                asm volatile("" :: "v"(acc[0]), "v"(acc[1]), "v"(acc[2]), "v"(acc[3]));
            }
        }
        asm volatile("" ::: "memory");
    }
}

// ---- Probe 3: pure linear streaming stores, full 131 MB per rep ----
__global__ void __launch_bounds__(256)
probe_store16(float* __restrict__ out) {
    const f32x4 v = {1.f, 2.f, 3.f, 4.f};
    const size_t gtid = (size_t)blockIdx.x * 256 + threadIdx.x;
    for (int rep = 0; rep < 16; ++rep) {
#pragma unroll
        for (int i = 0; i < 16; ++i)    // 16 x f32x4 per thread = 131 MB sweep
            *reinterpret_cast<f32x4*>(out + ((size_t)i * 524288 + gtid) * 4) = v;
        asm volatile("" ::: "memory");
    }
}

// ---- Probe 4: full algorithm, wave-private LDS epilogue, ZERO barriers ----
__global__ void __launch_bounds__(256)
probe_nobar16(const float* __restrict__ state, const float* __restrict__ W,
              const float* __restrict__ bias, float* __restrict__ out) {
    const int lane = threadIdx.x & 63;
    const int wave = threadIdx.x >> 6;
    const int l16  = lane & 15;
    const int lq   = lane >> 4;

    __shared__ float lds[4][16][68];     // wave-private [wave][row][col(64)+pad]

    bf16x8 wfrag[4][4];
    float  biasr[4];
    const int p       = wave >> 1;       // plane this wave owns
    const int colbase = (wave & 1) * 64; // cols within plane
#pragma unroll
    for (int ct = 0; ct < 4; ++ct) {
        const int n = colbase + ct * 16 + l16;
        const float* wrow = W + n * 256 + p * 128;
        biasr[ct] = bias[n * 2 + p];
#pragma unroll
        for (int ks = 0; ks < 4; ++ks) {
            f32x4 lo = *reinterpret_cast<const f32x4*>(wrow + ks * 32 + lq * 8);
            f32x4 hi = *reinterpret_cast<const f32x4*>(wrow + ks * 32 + lq * 8 + 4);
            wfrag[ct][ks] = cvt8(lo, hi);
        }
    }

    for (int rep = 0; rep < 16; ++rep) {
        for (int t = blockIdx.x; t < NTILES; t += GRID) {
            const float* srow = state + (size_t)(t * 16 + l16) * DDIM + lq * 8;
            f32x4 raw[8];
#pragma unroll
            for (int ks = 0; ks < 4; ++ks) {
                raw[2 * ks]     = *reinterpret_cast<const f32x4*>(srow + ks * 32);
                raw[2 * ks + 1] = *reinterpret_cast<const f32x4*>(srow + ks * 32 + 4);
            }
            bf16x8 af[4];
#pragma unroll
            for (int ks = 0; ks < 4; ++ks) af[ks] = cvt8(raw[2 * ks], raw[2 * ks + 1]);

#pragma unroll
            for (int ct = 0; ct < 4; ++ct) {
                f32x4 acc = {biasr[ct], biasr[ct], biasr[ct], biasr[ct]};
#pragma unroll
                for (int ks = 0; ks < 4; ++ks)
                    acc = __builtin_amdgcn_mfma_f32_16x16x32_bf16(af[ks], wfrag[ct][ks], acc, 0, 0, 0);
#pragma unroll
                for (int r = 0; r < 4; ++r)
                    lds[wave][lq * 4 + r][ct * 16 + l16] = acc[r];
            }
            __builtin_amdgcn_s_waitcnt(0);   // lgkmcnt(0): own-wave LDS writes done
            // wave-private drain: 4 stores, each = 4 rows x 256 B segments
#pragma unroll
            for (int i = 0; i < 4; ++i) {
                const int f   = i * 64 + lane;     // 0..255 f32x4 chunks
                const int row = f >> 4, c4 = f & 15;
                f32x4 v = *reinterpret_cast<f32x4*>(&lds[wave][row][c4 * 4]);
                *reinterpret_cast<f32x4*>(out + (size_t)p * BROWS * 128
                        + (size_t)(t * 16 + row) * 128 + colbase + c4 * 4) = v;
            }
        }
        asm volatile("" ::: "memory");
    }
}

// ---- Real kernel: R9 structure, 16 idempotent reps (correct output, anchor) ----
__global__ void __launch_bounds__(256)
lfm_full16(const float* __restrict__ state, const float* __restrict__ W,
           const float* __restrict__ bias, float* __restrict__ out) {
    const int lane = threadIdx.x & 63;
    const int wave = threadIdx.x >> 6;
    const int l16  = lane & 15;
    const int lq   = lane >> 4;

    __shared__ float lds[2 * 16 * 132];

    bf16x8 wfrag[4][4];
    float  biasr[4];
#pragma unroll
    for (int ct = 0; ct < 4; ++ct) {
        const int c = wave * 64 + ct * 16 + l16;
        const int n = c & 127, o = c >> 7;
        const float* wrow = W + n * 256 + o * 128;
        biasr[ct] = bias[n * 2 + o];
#pragma unroll
        for (int ks = 0; ks < 4; ++ks) {
            f32x4 lo = *reinterpret_cast<const f32x4*>(wrow + ks * 32 + lq * 8);
            f32x4 hi = *reinterpret_cast<const f32x4*>(wrow + ks * 32 + lq * 8 + 4);
            wfrag[ct][ks] = cvt8(lo, hi);
        }
    }

    for (int rep = 0; rep < 16; ++rep) {
        for (int t = blockIdx.x; t < NTILES; t += GRID) {
            const float* srow = state + (size_t)(t * 16 + l16) * DDIM + lq * 8;
            f32x4 raw[8];
#pragma unroll
            for (int ks = 0; ks < 4; ++ks) {
                raw[2 * ks]     = *reinterpret_cast<const f32x4*>(srow + ks * 32);
                raw[2 * ks + 1] = *reinterpret_cast<const f32x4*>(srow + ks * 32 + 4);
            }
            bf16x8 af[4];
#pragma unroll
            for (int ks = 0; ks < 4; ++ks) af[ks] = cvt8(raw[2 * ks], raw[2 * ks + 1]);

#pragma unroll
            for (int ct = 0; ct < 4; ++ct) {
                f32x4 acc = {biasr[ct], biasr[ct], biasr[ct], biasr[ct]};
#pragma unroll
                for (int ks = 0; ks < 4; ++ks)
                    acc = __builtin_amdgcn_mfma_f32_16x16x32_bf16(af[ks], wfrag[ct][ks], acc, 0, 0, 0);
                const int c   = wave * 64 + ct * 16 + l16;
                const int p   = c >> 7;
                const int col = c & 127;
#pragma unroll
                for (int r = 0; r < 4; ++r)
                    lds[(p * 16 + lq * 4 + r) * 132 + col] = acc[r];
            }
            __syncthreads();
#pragma unroll
            for (int j = 0; j < 4; ++j) {
                const int flat = j * 1024 + threadIdx.x * 4;
                const int pp   = flat >> 11;
                const int row  = (flat >> 7) & 15;
                f32x4 v = *reinterpret_cast<f32x4*>(&lds[(pp * 16 + row) * 132 + (flat & 127)]);
                *reinterpret_cast<f32x4*>(out + (size_t)pp * BROWS * 128
                                              + (size_t)t * 2048 + (flat & 2047)) = v;
            }
            __syncthreads();
        }
        asm volatile("" ::: "memory");
    }
}

extern "C" void kernel_launch(void* const* d_in, const int* in_sizes, int n_in,
                              void* d_out, int out_size, void* d_ws, size_t ws_size,
                              hipStream_t stream) {
    const float* state = (const float*)d_in[0];
    const float* W     = (const float*)d_in[1];
    const float* bias  = (const float*)d_in[2];
    float* out = (float*)d_out;

    hipLaunchKernelGGL(probe_copy32,  dim3(GRID), dim3(256), 0, stream, state, out);
    hipLaunchKernelGGL(probe_load32,  dim3(GRID), dim3(256), 0, stream, state, W);
    hipLaunchKernelGGL(probe_store16, dim3(GRID), dim3(256), 0, stream, out);
    hipLaunchKernelGGL(probe_nobar16, dim3(GRID), dim3(256), 0, stream, state, W, bias, out);
    hipLaunchKernelGGL(lfm_full16,    dim3(GRID), dim3(256), 0, stream, state, W, bias, out);
}